// Round 7
// baseline (849.139 us; speedup 1.0000x reference)
//
#include <hip/hip_runtime.h>
#include <hip/hip_bf16.h>

#define NN 50000
#define EE 1000000
#define FIN 512
#define HIDDEN 128
#define NH 8
#define DH 16
#define NOUT 3
#define NBUCK 196   // ceil(NN/256) coarse dst buckets

typedef unsigned short u16;
typedef unsigned int u32;
typedef __attribute__((ext_vector_type(8))) short short8;
typedef __attribute__((ext_vector_type(4))) float f32x4;

__device__ __forceinline__ float b2f(u16 b) { return __uint_as_float(((u32)b) << 16); }
__device__ __forceinline__ u16 f2b(float f) { return (u16)(__float_as_uint(f) >> 16); }

// Converted-weight layout (fp32), offsets within wconv:
#define W_WP   0
#define W_BP   65536
#define W_AS0  65664
#define W_AD0  65792
#define W_AS1  65920
#define W_AD1  66048
#define W_WK   66176
#define W_BK   82560
#define W_Q    82688
#define W_WL   82816
#define W_BL   83200
#define W_TOT  83203

// ---------------- Dtype detection ----------------
__global__ void k_detect(const void* __restrict__ x, int* __restrict__ flag)
{
    const u16* xb = (const u16*)x;
    int t = threadIdx.x;
    int insane = 0;
    #pragma unroll
    for (int i = 0; i < 16; ++i) {
        int idx = ((t * 16 + i) * 131) * 2;
        float v = b2f(xb[idx]);
        float a = fabsf(v);
        bool sane = (a == 0.0f) || (a >= 1e-8f && a <= 1e4f);
        insane += sane ? 0 : 1;
    }
    __shared__ int red[256];
    red[t] = insane;
    __syncthreads();
    for (int s = 128; s > 0; s >>= 1) { if (t < s) red[t] += red[t + s]; __syncthreads(); }
    if (t == 0) flag[0] = (red[0] > 1024) ? 1 : 0;   // 1 = fp32 inputs, 0 = bf16
}

// ---------------- Convert all small weights to canonical fp32 ----------------
__global__ __launch_bounds__(256) void k_convert(
    const void* Wp, const void* bp, const void* as0, const void* ad0,
    const void* as1, const void* ad1, const void* Wk, const void* bk,
    const void* q, const void* Wl, const void* bl,
    const int* __restrict__ flag, float* __restrict__ W)
{
    int i = blockIdx.x * 256 + threadIdx.x;
    if (i >= W_TOT) return;
    const void* src; int off;
    if      (i < W_BP)  { src = Wp;  off = i; }
    else if (i < W_AS0) { src = bp;  off = i - W_BP; }
    else if (i < W_AD0) { src = as0; off = i - W_AS0; }
    else if (i < W_AS1) { src = ad0; off = i - W_AD0; }
    else if (i < W_AD1) { src = as1; off = i - W_AS1; }
    else if (i < W_WK)  { src = ad1; off = i - W_AD1; }
    else if (i < W_BK)  { src = Wk;  off = i - W_WK; }
    else if (i < W_Q)   { src = bk;  off = i - W_BK; }
    else if (i < W_WL)  { src = q;   off = i - W_Q; }
    else if (i < W_BL)  { src = Wl;  off = i - W_WL; }
    else                { src = bl;  off = i - W_BL; }
    float v = flag[0] ? ((const float*)src)[off] : b2f(((const u16*)src)[off]);
    W[i] = v;
}

// ---------------- Prep: W_proj^T and Wk^T as bf16 hi/lo ----------------
#define PREPN (FIN*HIDDEN + HIDDEN*HIDDEN)   // 65536 + 16384
__global__ __launch_bounds__(256) void k_prepw(
    const float* __restrict__ Wpf, const float* __restrict__ Wkf,
    u16* __restrict__ WhiT, u16* __restrict__ WloT,
    u16* __restrict__ WkThi, u16* __restrict__ WkTlo)
{
    int idx = blockIdx.x*256 + threadIdx.x;
    if (idx >= PREPN) return;
    if (idx < FIN*HIDDEN) {
        int k = idx >> 7, n = idx & 127;
        float w = Wpf[idx];
        u32 hb = __float_as_uint(w) & 0xFFFF0000u;
        WhiT[(size_t)n*FIN + k] = (u16)(hb >> 16);
        WloT[(size_t)n*FIN + k] = f2b(w - __uint_as_float(hb));
    } else {
        int i = idx - FIN*HIDDEN;
        int k = i >> 7, h = i & 127;
        float w = Wkf[i];
        u32 hb = __float_as_uint(w) & 0xFFFF0000u;
        WkThi[(size_t)h*HIDDEN + k] = (u16)(hb >> 16);
        WkTlo[(size_t)h*HIDDEN + k] = f2b(w - __uint_as_float(hb));
    }
}

// ---------------- Projection via MFMA, split-bf16 ----------------
__global__ __launch_bounds__(256) void k_projm(
    const void* __restrict__ x, const u16* __restrict__ WhiT,
    const u16* __restrict__ WloT, const float* __restrict__ bpf,
    const int* __restrict__ flag, float* __restrict__ xp)
{
    const int t = threadIdx.x;
    const int lane = t & 63;
    const int w = t >> 6;
    const int m16 = lane & 15;
    const int quad = lane >> 4;
    const int f = flag[0];
    int row = blockIdx.x*64 + w*16 + m16;
    int rowc = row < NN ? row : NN-1;

    f32x4 acc[8];
    #pragma unroll
    for (int i=0;i<8;++i) acc[i] = (f32x4)(0.f);

    for (int kt = 0; kt < FIN; kt += 32) {
        int kbase = kt + quad*8;
        short8 ahi, alo;
        if (f) {
            const float* px = (const float*)x + (size_t)rowc*FIN + kbase;
            float4 v0 = *(const float4*)px;
            float4 v1 = *(const float4*)(px+4);
            float xv[8] = {v0.x,v0.y,v0.z,v0.w,v1.x,v1.y,v1.z,v1.w};
            #pragma unroll
            for (int j=0;j<8;++j) {
                u32 hb = __float_as_uint(xv[j]) & 0xFFFF0000u;
                ahi[j] = (short)(hb >> 16);
                alo[j] = (short)f2b(xv[j] - __uint_as_float(hb));
            }
        } else {
            const u16* px = (const u16*)x + (size_t)rowc*FIN + kbase;
            ushort4 v0 = *(const ushort4*)px;
            ushort4 v1 = *(const ushort4*)(px+4);
            ahi[0]=v0.x; ahi[1]=v0.y; ahi[2]=v0.z; ahi[3]=v0.w;
            ahi[4]=v1.x; ahi[5]=v1.y; ahi[6]=v1.z; ahi[7]=v1.w;
            alo = (short8)(short)0;
        }
        #pragma unroll
        for (int nt = 0; nt < 8; ++nt) {
            int n = nt*16 + m16;
            short8 bhi = *(const short8*)(WhiT + (size_t)n*FIN + kbase);
            short8 blo = *(const short8*)(WloT + (size_t)n*FIN + kbase);
            acc[nt] = __builtin_amdgcn_mfma_f32_16x16x32_bf16(ahi, bhi, acc[nt], 0,0,0);
            acc[nt] = __builtin_amdgcn_mfma_f32_16x16x32_bf16(ahi, blo, acc[nt], 0,0,0);
            acc[nt] = __builtin_amdgcn_mfma_f32_16x16x32_bf16(alo, bhi, acc[nt], 0,0,0);
        }
    }
    int orow0 = blockIdx.x*64 + w*16 + quad*4;
    #pragma unroll
    for (int nt=0; nt<8; ++nt) {
        int col = nt*16 + m16;
        float bias = bpf[col];
        #pragma unroll
        for (int r=0;r<4;++r) {
            int orow = orow0 + r;
            if (orow < NN) xp[(size_t)orow*HIDDEN + col] = acc[nt][r] + bias;
        }
    }
}

// ---------------- Attention coefficients ----------------
__global__ __launch_bounds__(256) void k_attcoef(
    const float* __restrict__ xp, const float* __restrict__ watt,
    float* __restrict__ o_as0, float* __restrict__ o_ad0,
    float* __restrict__ o_as1, float* __restrict__ o_ad1)
{
    __shared__ float s0[128], d0[128], s1[128], d1[128];
    const int t = threadIdx.x;
    if (t < 128) { s0[t]=watt[t]; d0[t]=watt[128+t]; s1[t]=watt[256+t]; d1[t]=watt[384+t]; }
    __syncthreads();
    int tid = blockIdx.x*256 + t;               // n*8 + h
    if (tid >= NN*NH) return;
    int h = tid & 7;
    const float4* px = (const float4*)(xp + (size_t)tid * DH);
    float xv[16];
    #pragma unroll
    for (int i=0;i<4;++i){ float4 v=px[i]; xv[i*4]=v.x; xv[i*4+1]=v.y; xv[i*4+2]=v.z; xv[i*4+3]=v.w; }
    float r0=0.f,r1=0.f,r2=0.f,r3=0.f;
    #pragma unroll
    for (int d=0; d<16; ++d) {
        float xvd = xv[d];
        r0 += xvd*s0[h*16+d]; r1 += xvd*d0[h*16+d];
        r2 += xvd*s1[h*16+d]; r3 += xvd*d1[h*16+d];
    }
    o_as0[tid]=r0; o_ad0[tid]=r1; o_as1[tid]=r2; o_ad1[tid]=r3;
}

// ---------------- CSR phase 1: histogram of dst ----------------
__global__ __launch_bounds__(256) void k_hist(
    const int* __restrict__ ei0, const int* __restrict__ ei1,
    int* __restrict__ cnt0, int* __restrict__ cnt1)
{
    int gid = blockIdx.x*256 + threadIdx.x;
    if (gid < EE)           atomicAdd(&cnt0[ei0[EE + gid]], 1);
    else if (gid < 2*EE)    atomicAdd(&cnt1[ei1[gid]], 1);
}

// ---------------- CSR phase 2: three-step parallel exclusive scan ----------------
#define NCH 49   // ceil(50001/1024)
__global__ __launch_bounds__(1024) void k_scan1(
    int* __restrict__ base0, int* __restrict__ base1, int* __restrict__ ssum)
{
    int mp = blockIdx.y;
    int* base = mp ? base1 : base0;
    __shared__ int s[1024];
    const int t = threadIdx.x;
    int i = blockIdx.x*1024 + t;
    int v = (i <= NN) ? base[i] : 0;
    s[t] = v;
    __syncthreads();
    for (int off = 1; off < 1024; off <<= 1) {
        int u = (t >= off) ? s[t - off] : 0;
        __syncthreads();
        s[t] += u;
        __syncthreads();
    }
    if (i <= NN) base[i] = s[t] - v;
    if (t == 1023) ssum[mp*64 + blockIdx.x] = s[1023];
}
__global__ void k_scan2(int* __restrict__ ssum)
{
    int t = threadIdx.x;
    if (t < 2) {
        int c = 0;
        for (int j = 0; j < NCH; ++j) { int v = ssum[t*64+j]; ssum[t*64+j] = c; c += v; }
    }
}
// also initializes fine cursors and the coarse (bucket) cursors, padded 16 ints apart
__global__ __launch_bounds__(1024) void k_scan3(
    int* __restrict__ base0, int* __restrict__ base1,
    int* __restrict__ cur0, int* __restrict__ cur1,
    const int* __restrict__ ssum, int* __restrict__ curA)
{
    int mp = blockIdx.y;
    int* base = mp ? base1 : base0;
    int* cur  = mp ? cur1  : cur0;
    int off = ssum[mp*64 + blockIdx.x];
    int i = blockIdx.x*1024 + threadIdx.x;
    if (i <= NN) {
        int b = base[i] + off;
        base[i] = b;
        if (i < NN) {
            cur[i] = b;
            if ((i & 255) == 0) curA[(mp*256 + (i >> 8)) * 16] = b;
        }
    }
}

// ---------------- Scatter pass A: coarse bucket binning (src,dst) ----------------
__global__ __launch_bounds__(256) void k_scatterA(
    const int* __restrict__ ei0, const int* __restrict__ ei1,
    int* __restrict__ curA, int2* __restrict__ tmp0, int2* __restrict__ tmp1)
{
    int gid = blockIdx.x*256 + threadIdx.x;
    if (gid < EE) {
        int s = ei0[gid], d = ei0[EE + gid];
        int pos = atomicAdd(&curA[(d >> 8) * 16], 1);
        tmp0[pos] = make_int2(s, d);
    } else if (gid < 2*EE) {
        int e = gid - EE;
        int s = ei1[e], d = ei1[gid];
        int pos = atomicAdd(&curA[(256 + (d >> 8)) * 16], 1);
        tmp1[pos] = make_int2(s, d);
    }
}

// ---------------- Scatter pass B: exact CSR position, one block per bucket ----------------
__global__ __launch_bounds__(256) void k_scatterB(
    const int2* __restrict__ tmp0, const int2* __restrict__ tmp1,
    const int* __restrict__ base0, const int* __restrict__ base1,
    int* __restrict__ cur0, int* __restrict__ cur1,
    int* __restrict__ srt0, int* __restrict__ srt1)
{
    const int b = blockIdx.x;
    const int mp = blockIdx.y;
    const int2* tmp = mp ? tmp1 : tmp0;
    const int* base = mp ? base1 : base0;
    int* cur = mp ? cur1 : cur0;
    int* srt = mp ? srt1 : srt0;
    int lo = base[b << 8];
    int hiIdx = (b + 1) << 8; if (hiIdx > NN) hiIdx = NN;
    int hi = base[hiIdx];
    for (int i = lo + threadIdx.x; i < hi; i += 256) {
        int2 sd = tmp[i];
        int pos = atomicAdd(&cur[sd.y], 1);
        srt[pos] = sd.x;
    }
}

// ---------------- Gather: one wave per dst node; fused softmax; 4x unroll ----------------
__global__ __launch_bounds__(256) void k_gather(
    const int* __restrict__ srt0, const int* __restrict__ srt1,
    const int* __restrict__ base0, const int* __restrict__ base1,
    const float* __restrict__ as0, const float* __restrict__ ad0,
    const float* __restrict__ as1, const float* __restrict__ ad1,
    const float* __restrict__ xp, float* __restrict__ o0, float* __restrict__ o1)
{
    const int t = threadIdx.x;
    const int wid = blockIdx.x*4 + (t >> 6);
    if (wid >= NN) return;
    const int lane = t & 63;
    const int h = lane >> 3;
    const int mp = blockIdx.y;
    const int*  srt  = mp ? srt1  : srt0;
    const int*  base = mp ? base1 : base0;
    const float* asr = mp ? as1 : as0;
    const float* ads = mp ? ad1 : ad0;
    float* o = mp ? o1 : o0;

    const int b = base[wid], e = base[wid + 1];
    const float advl = ads[wid*NH + h];
    float accx = 0.f, accy = 0.f, den = 0.f;
    int i = b;
    for (; i + 4 <= e; i += 4) {
        int s0 = srt[i], s1 = srt[i+1], s2 = srt[i+2], s3 = srt[i+3];
        float r0 = asr[s0*NH + h], r1 = asr[s1*NH + h];
        float r2 = asr[s2*NH + h], r3 = asr[s3*NH + h];
        float2 x0 = *(const float2*)&xp[(size_t)s0*HIDDEN + lane*2];
        float2 x1 = *(const float2*)&xp[(size_t)s1*HIDDEN + lane*2];
        float2 x2 = *(const float2*)&xp[(size_t)s2*HIDDEN + lane*2];
        float2 x3 = *(const float2*)&xp[(size_t)s3*HIDDEN + lane*2];
        float a0 = r0+advl; a0 = a0>0.f ? a0 : 0.2f*a0; float e0 = __expf(a0);
        float a1 = r1+advl; a1 = a1>0.f ? a1 : 0.2f*a1; float e1 = __expf(a1);
        float a2 = r2+advl; a2 = a2>0.f ? a2 : 0.2f*a2; float e2 = __expf(a2);
        float a3 = r3+advl; a3 = a3>0.f ? a3 : 0.2f*a3; float e3 = __expf(a3);
        accx += e0*x0.x + e1*x1.x + e2*x2.x + e3*x3.x;
        accy += e0*x0.y + e1*x1.y + e2*x2.y + e3*x3.y;
        den  += e0 + e1 + e2 + e3;
    }
    for (; i < e; ++i) {
        int s = srt[i];
        float a = asr[s*NH + h] + advl;
        a = a > 0.f ? a : 0.2f*a;
        float ex = __expf(a);
        float2 xv = *(const float2*)&xp[(size_t)s*HIDDEN + lane*2];
        accx += ex*xv.x; accy += ex*xv.y; den += ex;
    }
    float inv = 1.f / (den + 1e-16f);
    float2 r; r.x = accx*inv; r.y = accy*inv;
    *(float2*)&o[(size_t)wid*HIDDEN + lane*2] = r;
}

// ---------------- Semantic scores via MFMA ----------------
__global__ __launch_bounds__(256) void k_semantic(
    const float* __restrict__ o0, const float* __restrict__ o1,
    const u16* __restrict__ WkThi, const u16* __restrict__ WkTlo,
    const float* __restrict__ bkf, const float* __restrict__ qf,
    float* __restrict__ scores)
{
    const int t = threadIdx.x;
    const int lane = t & 63;
    const int w = t >> 6;
    const int m16 = lane & 15;
    const int quad = lane >> 4;
    const int mp = blockIdx.y;
    const float* om = mp ? o1 : o0;
    const int tile = blockIdx.x*4 + w;

    float partial = 0.f;
    if (tile < NN/16) {
        int row = tile*16 + m16;
        f32x4 acc[8];
        #pragma unroll
        for (int i=0;i<8;++i) acc[i] = (f32x4)(0.f);

        for (int kt = 0; kt < HIDDEN; kt += 32) {
            int kbase = kt + quad*8;
            const float* po = om + (size_t)row*HIDDEN + kbase;
            float4 v0 = *(const float4*)po;
            float4 v1 = *(const float4*)(po+4);
            float xv[8] = {v0.x,v0.y,v0.z,v0.w,v1.x,v1.y,v1.z,v1.w};
            short8 ahi, alo;
            #pragma unroll
            for (int j=0;j<8;++j) {
                float r = fmaxf(xv[j], 0.f);
                u32 hb = __float_as_uint(r) & 0xFFFF0000u;
                ahi[j] = (short)(hb >> 16);
                alo[j] = (short)f2b(r - __uint_as_float(hb));
            }
            #pragma unroll
            for (int nt = 0; nt < 8; ++nt) {
                int n = nt*16 + m16;
                short8 bhi = *(const short8*)(WkThi + (size_t)n*HIDDEN + kbase);
                short8 blo = *(const short8*)(WkTlo + (size_t)n*HIDDEN + kbase);
                acc[nt] = __builtin_amdgcn_mfma_f32_16x16x32_bf16(ahi, bhi, acc[nt], 0,0,0);
                acc[nt] = __builtin_amdgcn_mfma_f32_16x16x32_bf16(ahi, blo, acc[nt], 0,0,0);
                acc[nt] = __builtin_amdgcn_mfma_f32_16x16x32_bf16(alo, bhi, acc[nt], 0,0,0);
            }
        }
        #pragma unroll
        for (int nt=0; nt<8; ++nt) {
            int col = nt*16 + m16;
            float bkv = bkf[col], qv = qf[col];
            #pragma unroll
            for (int r=0;r<4;++r)
                partial += qv * tanhf(acc[nt][r] + bkv);
        }
    }
    __shared__ float red[256];
    red[t] = partial;
    __syncthreads();
    for (int s2 = 128; s2 > 0; s2 >>= 1) {
        if (t < s2) red[t] += red[t + s2];
        __syncthreads();
    }
    if (t == 0) unsafeAtomicAdd(&scores[mp], red[0]);
}

// ---------------- Beta ----------------
__global__ void k_beta(const float* __restrict__ scores, float* __restrict__ beta)
{
    float s0 = scores[0] / (float)NN;
    float s1 = scores[1] / (float)NN;
    float m = fmaxf(s0, s1);
    float e0 = __expf(s0-m), e1 = __expf(s1-m);
    float inv = 1.f/(e0+e1);
    beta[0] = e0*inv; beta[1] = e1*inv;
}

// ---------------- Final head ----------------
__global__ __launch_bounds__(256) void k_final(
    const float* __restrict__ o0, const float* __restrict__ o1,
    const float* __restrict__ beta, const float* __restrict__ Wlf,
    const float* __restrict__ blf, const int* __restrict__ flag,
    void* __restrict__ outv)
{
    __shared__ float fus[16*128];
    __shared__ float WlL[384];
    __shared__ float blL[3];
    const int t = threadIdx.x;
    for (int i = t; i < 384; i += 256) WlL[i] = Wlf[i];
    if (t < 3) blL[t] = blf[t];
    float b0 = beta[0], b1 = beta[1];
    size_t base = (size_t)blockIdx.x * 16 * HIDDEN;
    #pragma unroll
    for (int i=0;i<8;++i) {
        int idx = t + i*256;
        fus[idx] = b0*fmaxf(o0[base+idx],0.f) + b1*fmaxf(o1[base+idx],0.f);
    }
    __syncthreads();
    if (t < 48) {
        int node = t / 3, c = t % 3;
        float acc = blL[c];
        const float* fr = &fus[node*128];
        #pragma unroll 16
        for (int k=0;k<128;++k) acc += fr[k]*WlL[k*3+c];
        size_t oi = (size_t)(blockIdx.x*16 + node)*NOUT + c;
        if (flag[0]) ((float*)outv)[oi] = acc;
        else         ((__hip_bfloat16*)outv)[oi] = __float2bfloat16(acc);
    }
}

extern "C" void kernel_launch(void* const* d_in, const int* in_sizes, int n_in,
                              void* d_out, int out_size, void* d_ws, size_t ws_size,
                              hipStream_t stream)
{
    const void* x   = d_in[0];
    const int* ei0  = (const int*)d_in[1];
    const int* ei1  = (const int*)d_in[2];

    float* ws = (float*)d_ws;
    float* xp      = ws;                        // 6,400,000
    float* a_src0  = ws +  6400000;
    float* a_dst0  = ws +  6800000;
    float* a_src1  = ws +  7200000;
    float* a_dst1  = ws +  7600000;
    float* o0      = ws +  8000000;             // 6,400,000 (tmp0 aliases: 2M int2 = 4M f)
    float* o1      = ws + 14400000;             // 6,400,000 (tmp1 aliases)
    int*   srt0    = (int*)(ws + 20800000);     // 1,000,000
    int*   srt1    = (int*)(ws + 21800000);     // 1,000,000
    int*   base0   = (int*)(ws + 22800000);     // 50,004
    int*   base1   = (int*)(ws + 22850004);     // 50,004
    float* scores  = ws + 22900008;             // 2
    int*   cur0    = (int*)(ws + 22900010);     // 50,000
    int*   cur1    = (int*)(ws + 22950010);     // 50,000
    float* beta    = ws + 23000010;             // 2
    int*   flag    = (int*)(ws + 23000012);     // 4 (pad)
    float* wconv   = ws + 23000016;             // 83,203
    int*   ssum    = (int*)(ws + 23083220);     // 128
    u16*   WhiT    = (u16*)(ws + 23083348);     // 65,536 u16 = 32,768 f
    u16*   WloT    = (u16*)(ws + 23116116);     // 65,536 u16
    u16*   WkThi   = (u16*)(ws + 23148884);     // 16,384 u16 = 8,192 f
    u16*   WkTlo   = (u16*)(ws + 23157076);     // 16,384 u16
    int*   curA    = (int*)(ws + 23165268);     // 2*256*16 = 8,192 ints (64B-padded cursors)
    int2*  tmp0    = (int2*)o0;                 // dead until k_gather writes o0
    int2*  tmp1    = (int2*)o1;
    // total ≈ 23,173,460 floats ≈ 92.7 MB

    hipMemsetAsync(base0, 0, (size_t)100010 * sizeof(int), stream);

    k_detect<<<1, 256, 0, stream>>>(x, flag);
    k_convert<<<(W_TOT+255)/256, 256, 0, stream>>>(
        d_in[3], d_in[4], d_in[5], d_in[6], d_in[7], d_in[8],
        d_in[9], d_in[10], d_in[11], d_in[12], d_in[13], flag, wconv);
    k_prepw<<<(PREPN+255)/256, 256, 0, stream>>>(wconv + W_WP, wconv + W_WK,
                                                 WhiT, WloT, WkThi, WkTlo);

    k_projm<<<(NN+63)/64, 256, 0, stream>>>(x, WhiT, WloT, wconv + W_BP, flag, xp);
    k_attcoef<<<(NN*NH + 255)/256, 256, 0, stream>>>(xp, wconv + W_AS0,
                                                     a_src0, a_dst0, a_src1, a_dst1);
    k_hist<<<(2*EE + 255)/256, 256, 0, stream>>>(ei0, ei1, base0, base1);
    k_scan1<<<dim3(NCH,2), 1024, 0, stream>>>(base0, base1, ssum);
    k_scan2<<<1, 64, 0, stream>>>(ssum);
    k_scan3<<<dim3(NCH,2), 1024, 0, stream>>>(base0, base1, cur0, cur1, ssum, curA);
    k_scatterA<<<(2*EE + 255)/256, 256, 0, stream>>>(ei0, ei1, curA, tmp0, tmp1);
    k_scatterB<<<dim3(NBUCK,2), 256, 0, stream>>>(tmp0, tmp1, base0, base1,
                                                  cur0, cur1, srt0, srt1);
    k_gather<<<dim3((NN + 3)/4, 2), 256, 0, stream>>>(
        srt0, srt1, base0, base1, a_src0, a_dst0, a_src1, a_dst1, xp, o0, o1);

    k_semantic<<<dim3((NN/16 + 3)/4, 2), 256, 0, stream>>>(
        o0, o1, WkThi, WkTlo, wconv + W_BK, wconv + W_Q, scores);
    k_beta<<<1, 1, 0, stream>>>(scores, beta);
    k_final<<<NN/16, 256, 0, stream>>>(o0, o1, beta, wconv + W_WL, wconv + W_BL,
                                       flag, d_out);
}

// Round 8
// 692.535 us; speedup vs baseline: 1.2261x; 1.2261x over previous
//
#include <hip/hip_runtime.h>
#include <hip/hip_bf16.h>

#define NN 50000
#define EE 1000000
#define FIN 512
#define HIDDEN 128
#define NH 8
#define DH 16
#define NOUT 3
#define NBUCK 196   // ceil(NN/256) coarse dst buckets
#define EPB 8192    // edges per block in scatterA
#define NBLKA ((EE + EPB - 1) / EPB)

typedef unsigned short u16;
typedef unsigned int u32;
typedef __attribute__((ext_vector_type(8))) short short8;
typedef __attribute__((ext_vector_type(4))) float f32x4;

__device__ __forceinline__ float b2f(u16 b) { return __uint_as_float(((u32)b) << 16); }
__device__ __forceinline__ u16 f2b(float f) { return (u16)(__float_as_uint(f) >> 16); }

// Converted-weight layout (fp32), offsets within wconv:
#define W_WP   0
#define W_BP   65536
#define W_AS0  65664
#define W_AD0  65792
#define W_AS1  65920
#define W_AD1  66048
#define W_WK   66176
#define W_BK   82560
#define W_Q    82688
#define W_WL   82816
#define W_BL   83200
#define W_TOT  83203

// ---------------- Dtype detection ----------------
__global__ void k_detect(const void* __restrict__ x, int* __restrict__ flag)
{
    const u16* xb = (const u16*)x;
    int t = threadIdx.x;
    int insane = 0;
    #pragma unroll
    for (int i = 0; i < 16; ++i) {
        int idx = ((t * 16 + i) * 131) * 2;
        float v = b2f(xb[idx]);
        float a = fabsf(v);
        bool sane = (a == 0.0f) || (a >= 1e-8f && a <= 1e4f);
        insane += sane ? 0 : 1;
    }
    __shared__ int red[256];
    red[t] = insane;
    __syncthreads();
    for (int s = 128; s > 0; s >>= 1) { if (t < s) red[t] += red[t + s]; __syncthreads(); }
    if (t == 0) flag[0] = (red[0] > 1024) ? 1 : 0;   // 1 = fp32 inputs, 0 = bf16
}

// ---------------- Convert all small weights to canonical fp32 ----------------
__global__ __launch_bounds__(256) void k_convert(
    const void* Wp, const void* bp, const void* as0, const void* ad0,
    const void* as1, const void* ad1, const void* Wk, const void* bk,
    const void* q, const void* Wl, const void* bl,
    const int* __restrict__ flag, float* __restrict__ W)
{
    int i = blockIdx.x * 256 + threadIdx.x;
    if (i >= W_TOT) return;
    const void* src; int off;
    if      (i < W_BP)  { src = Wp;  off = i; }
    else if (i < W_AS0) { src = bp;  off = i - W_BP; }
    else if (i < W_AD0) { src = as0; off = i - W_AS0; }
    else if (i < W_AS1) { src = ad0; off = i - W_AD0; }
    else if (i < W_AD1) { src = as1; off = i - W_AS1; }
    else if (i < W_WK)  { src = ad1; off = i - W_AD1; }
    else if (i < W_BK)  { src = Wk;  off = i - W_WK; }
    else if (i < W_Q)   { src = bk;  off = i - W_BK; }
    else if (i < W_WL)  { src = q;   off = i - W_Q; }
    else if (i < W_BL)  { src = Wl;  off = i - W_WL; }
    else                { src = bl;  off = i - W_BL; }
    float v = flag[0] ? ((const float*)src)[off] : b2f(((const u16*)src)[off]);
    W[i] = v;
}

// ---------------- Prep: W_proj^T and Wk^T as bf16 hi/lo ----------------
#define PREPN (FIN*HIDDEN + HIDDEN*HIDDEN)   // 65536 + 16384
__global__ __launch_bounds__(256) void k_prepw(
    const float* __restrict__ Wpf, const float* __restrict__ Wkf,
    u16* __restrict__ WhiT, u16* __restrict__ WloT,
    u16* __restrict__ WkThi, u16* __restrict__ WkTlo)
{
    int idx = blockIdx.x*256 + threadIdx.x;
    if (idx >= PREPN) return;
    if (idx < FIN*HIDDEN) {
        int k = idx >> 7, n = idx & 127;
        float w = Wpf[idx];
        u32 hb = __float_as_uint(w) & 0xFFFF0000u;
        WhiT[(size_t)n*FIN + k] = (u16)(hb >> 16);
        WloT[(size_t)n*FIN + k] = f2b(w - __uint_as_float(hb));
    } else {
        int i = idx - FIN*HIDDEN;
        int k = i >> 7, h = i & 127;
        float w = Wkf[i];
        u32 hb = __float_as_uint(w) & 0xFFFF0000u;
        WkThi[(size_t)h*HIDDEN + k] = (u16)(hb >> 16);
        WkTlo[(size_t)h*HIDDEN + k] = f2b(w - __uint_as_float(hb));
    }
}

// ---------------- Projection via MFMA, split-bf16 ----------------
__global__ __launch_bounds__(256) void k_projm(
    const void* __restrict__ x, const u16* __restrict__ WhiT,
    const u16* __restrict__ WloT, const float* __restrict__ bpf,
    const int* __restrict__ flag, float* __restrict__ xp)
{
    const int t = threadIdx.x;
    const int lane = t & 63;
    const int w = t >> 6;
    const int m16 = lane & 15;
    const int quad = lane >> 4;
    const int f = flag[0];
    int row = blockIdx.x*64 + w*16 + m16;
    int rowc = row < NN ? row : NN-1;

    f32x4 acc[8];
    #pragma unroll
    for (int i=0;i<8;++i) acc[i] = (f32x4)(0.f);

    for (int kt = 0; kt < FIN; kt += 32) {
        int kbase = kt + quad*8;
        short8 ahi, alo;
        if (f) {
            const float* px = (const float*)x + (size_t)rowc*FIN + kbase;
            float4 v0 = *(const float4*)px;
            float4 v1 = *(const float4*)(px+4);
            float xv[8] = {v0.x,v0.y,v0.z,v0.w,v1.x,v1.y,v1.z,v1.w};
            #pragma unroll
            for (int j=0;j<8;++j) {
                u32 hb = __float_as_uint(xv[j]) & 0xFFFF0000u;
                ahi[j] = (short)(hb >> 16);
                alo[j] = (short)f2b(xv[j] - __uint_as_float(hb));
            }
        } else {
            const u16* px = (const u16*)x + (size_t)rowc*FIN + kbase;
            ushort4 v0 = *(const ushort4*)px;
            ushort4 v1 = *(const ushort4*)(px+4);
            ahi[0]=v0.x; ahi[1]=v0.y; ahi[2]=v0.z; ahi[3]=v0.w;
            ahi[4]=v1.x; ahi[5]=v1.y; ahi[6]=v1.z; ahi[7]=v1.w;
            alo = (short8)(short)0;
        }
        #pragma unroll
        for (int nt = 0; nt < 8; ++nt) {
            int n = nt*16 + m16;
            short8 bhi = *(const short8*)(WhiT + (size_t)n*FIN + kbase);
            short8 blo = *(const short8*)(WloT + (size_t)n*FIN + kbase);
            acc[nt] = __builtin_amdgcn_mfma_f32_16x16x32_bf16(ahi, bhi, acc[nt], 0,0,0);
            acc[nt] = __builtin_amdgcn_mfma_f32_16x16x32_bf16(ahi, blo, acc[nt], 0,0,0);
            acc[nt] = __builtin_amdgcn_mfma_f32_16x16x32_bf16(alo, bhi, acc[nt], 0,0,0);
        }
    }
    int orow0 = blockIdx.x*64 + w*16 + quad*4;
    #pragma unroll
    for (int nt=0; nt<8; ++nt) {
        int col = nt*16 + m16;
        float bias = bpf[col];
        #pragma unroll
        for (int r=0;r<4;++r) {
            int orow = orow0 + r;
            if (orow < NN) xp[(size_t)orow*HIDDEN + col] = acc[nt][r] + bias;
        }
    }
}

// ---------------- Attention coefficients ----------------
__global__ __launch_bounds__(256) void k_attcoef(
    const float* __restrict__ xp, const float* __restrict__ watt,
    float* __restrict__ o_as0, float* __restrict__ o_ad0,
    float* __restrict__ o_as1, float* __restrict__ o_ad1)
{
    __shared__ float s0[128], d0[128], s1[128], d1[128];
    const int t = threadIdx.x;
    if (t < 128) { s0[t]=watt[t]; d0[t]=watt[128+t]; s1[t]=watt[256+t]; d1[t]=watt[384+t]; }
    __syncthreads();
    int tid = blockIdx.x*256 + t;               // n*8 + h
    if (tid >= NN*NH) return;
    int h = tid & 7;
    const float4* px = (const float4*)(xp + (size_t)tid * DH);
    float xv[16];
    #pragma unroll
    for (int i=0;i<4;++i){ float4 v=px[i]; xv[i*4]=v.x; xv[i*4+1]=v.y; xv[i*4+2]=v.z; xv[i*4+3]=v.w; }
    float r0=0.f,r1=0.f,r2=0.f,r3=0.f;
    #pragma unroll
    for (int d=0; d<16; ++d) {
        float xvd = xv[d];
        r0 += xvd*s0[h*16+d]; r1 += xvd*d0[h*16+d];
        r2 += xvd*s1[h*16+d]; r3 += xvd*d1[h*16+d];
    }
    o_as0[tid]=r0; o_ad0[tid]=r1; o_as1[tid]=r2; o_ad1[tid]=r3;
}

// ---------------- CSR phase 1: histogram of dst ----------------
__global__ __launch_bounds__(256) void k_hist(
    const int* __restrict__ ei0, const int* __restrict__ ei1,
    int* __restrict__ cnt0, int* __restrict__ cnt1)
{
    int gid = blockIdx.x*256 + threadIdx.x;
    if (gid < EE)           atomicAdd(&cnt0[ei0[EE + gid]], 1);
    else if (gid < 2*EE)    atomicAdd(&cnt1[ei1[gid]], 1);
}

// ---------------- CSR phase 2: three-step parallel exclusive scan ----------------
#define NCH 49   // ceil(50001/1024)
__global__ __launch_bounds__(1024) void k_scan1(
    int* __restrict__ base0, int* __restrict__ base1, int* __restrict__ ssum)
{
    int mp = blockIdx.y;
    int* base = mp ? base1 : base0;
    __shared__ int s[1024];
    const int t = threadIdx.x;
    int i = blockIdx.x*1024 + t;
    int v = (i <= NN) ? base[i] : 0;
    s[t] = v;
    __syncthreads();
    for (int off = 1; off < 1024; off <<= 1) {
        int u = (t >= off) ? s[t - off] : 0;
        __syncthreads();
        s[t] += u;
        __syncthreads();
    }
    if (i <= NN) base[i] = s[t] - v;
    if (t == 1023) ssum[mp*64 + blockIdx.x] = s[1023];
}
__global__ void k_scan2(int* __restrict__ ssum)
{
    int t = threadIdx.x;
    if (t < 2) {
        int c = 0;
        for (int j = 0; j < NCH; ++j) { int v = ssum[t*64+j]; ssum[t*64+j] = c; c += v; }
    }
}
// also initializes fine cursors and the coarse (bucket) cursors, padded 16 ints apart
__global__ __launch_bounds__(1024) void k_scan3(
    int* __restrict__ base0, int* __restrict__ base1,
    int* __restrict__ cur0, int* __restrict__ cur1,
    const int* __restrict__ ssum, int* __restrict__ curA)
{
    int mp = blockIdx.y;
    int* base = mp ? base1 : base0;
    int* cur  = mp ? cur1  : cur0;
    int off = ssum[mp*64 + blockIdx.x];
    int i = blockIdx.x*1024 + threadIdx.x;
    if (i <= NN) {
        int b = base[i] + off;
        base[i] = b;
        if (i < NN) {
            cur[i] = b;
            if ((i & 255) == 0) curA[(mp*256 + (i >> 8)) * 16] = b;
        }
    }
}

// ---------------- Scatter pass A: reserve-segment coarse binning ----------------
// Each block owns contiguous per-(block,bucket) output segments -> every cache
// line written by exactly one block (one XCD) -> writeback amplification ~1.
__global__ __launch_bounds__(256) void k_scatterA(
    const int* __restrict__ ei0, const int* __restrict__ ei1,
    int* __restrict__ curA, int2* __restrict__ tmp0, int2* __restrict__ tmp1)
{
    const int mp = blockIdx.y;
    const int* ei = mp ? ei1 : ei0;
    int2* tmp = mp ? tmp1 : tmp0;
    __shared__ int hist[NBUCK];
    __shared__ int seg[NBUCK];
    __shared__ int cnt[NBUCK];
    const int t = threadIdx.x;
    for (int b = t; b < NBUCK; b += 256) hist[b] = 0;
    __syncthreads();
    const int e0 = blockIdx.x * EPB;
    // phase 1: local histogram
    #pragma unroll
    for (int i = 0; i < EPB/256; ++i) {
        int idx = e0 + i*256 + t;
        if (idx < EE) atomicAdd(&hist[ei[EE + idx] >> 8], 1);
    }
    __syncthreads();
    // reserve one contiguous segment per non-empty bucket
    for (int b = t; b < NBUCK; b += 256) {
        int h = hist[b];
        seg[b] = h ? atomicAdd(&curA[(mp*256 + b)*16], h) : 0;
        cnt[b] = 0;
    }
    __syncthreads();
    // phase 2: write into owned segments
    #pragma unroll
    for (int i = 0; i < EPB/256; ++i) {
        int idx = e0 + i*256 + t;
        if (idx < EE) {
            int s = ei[idx], d = ei[EE + idx];
            int b = d >> 8;
            int pos = seg[b] + atomicAdd(&cnt[b], 1);
            tmp[pos] = make_int2(s, d);
        }
    }
}

// ---------------- Scatter pass B: exact CSR position, one block per bucket ----------------
__global__ __launch_bounds__(256) void k_scatterB(
    const int2* __restrict__ tmp0, const int2* __restrict__ tmp1,
    const int* __restrict__ base0, const int* __restrict__ base1,
    int* __restrict__ cur0, int* __restrict__ cur1,
    int* __restrict__ srt0, int* __restrict__ srt1)
{
    const int b = blockIdx.x;
    const int mp = blockIdx.y;
    const int2* tmp = mp ? tmp1 : tmp0;
    const int* base = mp ? base1 : base0;
    int* cur = mp ? cur1 : cur0;
    int* srt = mp ? srt1 : srt0;
    int lo = base[b << 8];
    int hiIdx = (b + 1) << 8; if (hiIdx > NN) hiIdx = NN;
    int hi = base[hiIdx];
    for (int i = lo + threadIdx.x; i < hi; i += 256) {
        int2 sd = tmp[i];
        int pos = atomicAdd(&cur[sd.y], 1);
        srt[pos] = sd.x;
    }
}

// ---------------- Gather: one wave per dst node; fused softmax; 4x unroll ----------------
__global__ __launch_bounds__(256) void k_gather(
    const int* __restrict__ srt0, const int* __restrict__ srt1,
    const int* __restrict__ base0, const int* __restrict__ base1,
    const float* __restrict__ as0, const float* __restrict__ ad0,
    const float* __restrict__ as1, const float* __restrict__ ad1,
    const float* __restrict__ xp, float* __restrict__ o0, float* __restrict__ o1)
{
    const int t = threadIdx.x;
    const int wid = blockIdx.x*4 + (t >> 6);
    if (wid >= NN) return;
    const int lane = t & 63;
    const int h = lane >> 3;
    const int mp = blockIdx.y;
    const int*  srt  = mp ? srt1  : srt0;
    const int*  base = mp ? base1 : base0;
    const float* asr = mp ? as1 : as0;
    const float* ads = mp ? ad1 : ad0;
    float* o = mp ? o1 : o0;

    const int b = base[wid], e = base[wid + 1];
    const float advl = ads[wid*NH + h];
    float accx = 0.f, accy = 0.f, den = 0.f;
    int i = b;
    for (; i + 4 <= e; i += 4) {
        int s0 = srt[i], s1 = srt[i+1], s2 = srt[i+2], s3 = srt[i+3];
        float r0 = asr[s0*NH + h], r1 = asr[s1*NH + h];
        float r2 = asr[s2*NH + h], r3 = asr[s3*NH + h];
        float2 x0 = *(const float2*)&xp[(size_t)s0*HIDDEN + lane*2];
        float2 x1 = *(const float2*)&xp[(size_t)s1*HIDDEN + lane*2];
        float2 x2 = *(const float2*)&xp[(size_t)s2*HIDDEN + lane*2];
        float2 x3 = *(const float2*)&xp[(size_t)s3*HIDDEN + lane*2];
        float a0 = r0+advl; a0 = a0>0.f ? a0 : 0.2f*a0; float e0 = __expf(a0);
        float a1 = r1+advl; a1 = a1>0.f ? a1 : 0.2f*a1; float e1 = __expf(a1);
        float a2 = r2+advl; a2 = a2>0.f ? a2 : 0.2f*a2; float e2 = __expf(a2);
        float a3 = r3+advl; a3 = a3>0.f ? a3 : 0.2f*a3; float e3 = __expf(a3);
        accx += e0*x0.x + e1*x1.x + e2*x2.x + e3*x3.x;
        accy += e0*x0.y + e1*x1.y + e2*x2.y + e3*x3.y;
        den  += e0 + e1 + e2 + e3;
    }
    for (; i < e; ++i) {
        int s = srt[i];
        float a = asr[s*NH + h] + advl;
        a = a > 0.f ? a : 0.2f*a;
        float ex = __expf(a);
        float2 xv = *(const float2*)&xp[(size_t)s*HIDDEN + lane*2];
        accx += ex*xv.x; accy += ex*xv.y; den += ex;
    }
    float inv = 1.f / (den + 1e-16f);
    float2 r; r.x = accx*inv; r.y = accy*inv;
    *(float2*)&o[(size_t)wid*HIDDEN + lane*2] = r;
}

// ---------------- Semantic scores via MFMA ----------------
__global__ __launch_bounds__(256) void k_semantic(
    const float* __restrict__ o0, const float* __restrict__ o1,
    const u16* __restrict__ WkThi, const u16* __restrict__ WkTlo,
    const float* __restrict__ bkf, const float* __restrict__ qf,
    float* __restrict__ scores)
{
    const int t = threadIdx.x;
    const int lane = t & 63;
    const int w = t >> 6;
    const int m16 = lane & 15;
    const int quad = lane >> 4;
    const int mp = blockIdx.y;
    const float* om = mp ? o1 : o0;
    const int tile = blockIdx.x*4 + w;

    float partial = 0.f;
    if (tile < NN/16) {
        int row = tile*16 + m16;
        f32x4 acc[8];
        #pragma unroll
        for (int i=0;i<8;++i) acc[i] = (f32x4)(0.f);

        for (int kt = 0; kt < HIDDEN; kt += 32) {
            int kbase = kt + quad*8;
            const float* po = om + (size_t)row*HIDDEN + kbase;
            float4 v0 = *(const float4*)po;
            float4 v1 = *(const float4*)(po+4);
            float xv[8] = {v0.x,v0.y,v0.z,v0.w,v1.x,v1.y,v1.z,v1.w};
            short8 ahi, alo;
            #pragma unroll
            for (int j=0;j<8;++j) {
                float r = fmaxf(xv[j], 0.f);
                u32 hb = __float_as_uint(r) & 0xFFFF0000u;
                ahi[j] = (short)(hb >> 16);
                alo[j] = (short)f2b(r - __uint_as_float(hb));
            }
            #pragma unroll
            for (int nt = 0; nt < 8; ++nt) {
                int n = nt*16 + m16;
                short8 bhi = *(const short8*)(WkThi + (size_t)n*HIDDEN + kbase);
                short8 blo = *(const short8*)(WkTlo + (size_t)n*HIDDEN + kbase);
                acc[nt] = __builtin_amdgcn_mfma_f32_16x16x32_bf16(ahi, bhi, acc[nt], 0,0,0);
                acc[nt] = __builtin_amdgcn_mfma_f32_16x16x32_bf16(ahi, blo, acc[nt], 0,0,0);
                acc[nt] = __builtin_amdgcn_mfma_f32_16x16x32_bf16(alo, bhi, acc[nt], 0,0,0);
            }
        }
        #pragma unroll
        for (int nt=0; nt<8; ++nt) {
            int col = nt*16 + m16;
            float bkv = bkf[col], qv = qf[col];
            #pragma unroll
            for (int r=0;r<4;++r)
                partial += qv * tanhf(acc[nt][r] + bkv);
        }
    }
    __shared__ float red[256];
    red[t] = partial;
    __syncthreads();
    for (int s2 = 128; s2 > 0; s2 >>= 1) {
        if (t < s2) red[t] += red[t + s2];
        __syncthreads();
    }
    if (t == 0) unsafeAtomicAdd(&scores[mp], red[0]);
}

// ---------------- Beta ----------------
__global__ void k_beta(const float* __restrict__ scores, float* __restrict__ beta)
{
    float s0 = scores[0] / (float)NN;
    float s1 = scores[1] / (float)NN;
    float m = fmaxf(s0, s1);
    float e0 = __expf(s0-m), e1 = __expf(s1-m);
    float inv = 1.f/(e0+e1);
    beta[0] = e0*inv; beta[1] = e1*inv;
}

// ---------------- Final head ----------------
__global__ __launch_bounds__(256) void k_final(
    const float* __restrict__ o0, const float* __restrict__ o1,
    const float* __restrict__ beta, const float* __restrict__ Wlf,
    const float* __restrict__ blf, const int* __restrict__ flag,
    void* __restrict__ outv)
{
    __shared__ float fus[16*128];
    __shared__ float WlL[384];
    __shared__ float blL[3];
    const int t = threadIdx.x;
    for (int i = t; i < 384; i += 256) WlL[i] = Wlf[i];
    if (t < 3) blL[t] = blf[t];
    float b0 = beta[0], b1 = beta[1];
    size_t base = (size_t)blockIdx.x * 16 * HIDDEN;
    #pragma unroll
    for (int i=0;i<8;++i) {
        int idx = t + i*256;
        fus[idx] = b0*fmaxf(o0[base+idx],0.f) + b1*fmaxf(o1[base+idx],0.f);
    }
    __syncthreads();
    if (t < 48) {
        int node = t / 3, c = t % 3;
        float acc = blL[c];
        const float* fr = &fus[node*128];
        #pragma unroll 16
        for (int k=0;k<128;++k) acc += fr[k]*WlL[k*3+c];
        size_t oi = (size_t)(blockIdx.x*16 + node)*NOUT + c;
        if (flag[0]) ((float*)outv)[oi] = acc;
        else         ((__hip_bfloat16*)outv)[oi] = __float2bfloat16(acc);
    }
}

extern "C" void kernel_launch(void* const* d_in, const int* in_sizes, int n_in,
                              void* d_out, int out_size, void* d_ws, size_t ws_size,
                              hipStream_t stream)
{
    const void* x   = d_in[0];
    const int* ei0  = (const int*)d_in[1];
    const int* ei1  = (const int*)d_in[2];

    float* ws = (float*)d_ws;
    float* xp      = ws;                        // 6,400,000
    float* a_src0  = ws +  6400000;
    float* a_dst0  = ws +  6800000;
    float* a_src1  = ws +  7200000;
    float* a_dst1  = ws +  7600000;
    float* o0      = ws +  8000000;             // 6,400,000 (tmp0 aliases: 2M int2 = 4M f)
    float* o1      = ws + 14400000;             // 6,400,000 (tmp1 aliases)
    int*   srt0    = (int*)(ws + 20800000);     // 1,000,000
    int*   srt1    = (int*)(ws + 21800000);     // 1,000,000
    int*   base0   = (int*)(ws + 22800000);     // 50,004
    int*   base1   = (int*)(ws + 22850004);     // 50,004
    float* scores  = ws + 22900008;             // 2
    int*   cur0    = (int*)(ws + 22900010);     // 50,000
    int*   cur1    = (int*)(ws + 22950010);     // 50,000
    float* beta    = ws + 23000010;             // 2
    int*   flag    = (int*)(ws + 23000012);     // 4 (pad)
    float* wconv   = ws + 23000016;             // 83,203
    int*   ssum    = (int*)(ws + 23083220);     // 128
    u16*   WhiT    = (u16*)(ws + 23083348);     // 65,536 u16 = 32,768 f
    u16*   WloT    = (u16*)(ws + 23116116);     // 65,536 u16
    u16*   WkThi   = (u16*)(ws + 23148884);     // 16,384 u16 = 8,192 f
    u16*   WkTlo   = (u16*)(ws + 23157076);     // 16,384 u16
    int*   curA    = (int*)(ws + 23165268);     // 2*256*16 = 8,192 ints (64B-padded cursors)
    int2*  tmp0    = (int2*)o0;                 // dead until k_gather writes o0
    int2*  tmp1    = (int2*)o1;
    // total ≈ 23,173,460 floats ≈ 92.7 MB

    hipMemsetAsync(base0, 0, (size_t)100010 * sizeof(int), stream);

    k_detect<<<1, 256, 0, stream>>>(x, flag);
    k_convert<<<(W_TOT+255)/256, 256, 0, stream>>>(
        d_in[3], d_in[4], d_in[5], d_in[6], d_in[7], d_in[8],
        d_in[9], d_in[10], d_in[11], d_in[12], d_in[13], flag, wconv);
    k_prepw<<<(PREPN+255)/256, 256, 0, stream>>>(wconv + W_WP, wconv + W_WK,
                                                 WhiT, WloT, WkThi, WkTlo);

    k_projm<<<(NN+63)/64, 256, 0, stream>>>(x, WhiT, WloT, wconv + W_BP, flag, xp);
    k_attcoef<<<(NN*NH + 255)/256, 256, 0, stream>>>(xp, wconv + W_AS0,
                                                     a_src0, a_dst0, a_src1, a_dst1);
    k_hist<<<(2*EE + 255)/256, 256, 0, stream>>>(ei0, ei1, base0, base1);
    k_scan1<<<dim3(NCH,2), 1024, 0, stream>>>(base0, base1, ssum);
    k_scan2<<<1, 64, 0, stream>>>(ssum);
    k_scan3<<<dim3(NCH,2), 1024, 0, stream>>>(base0, base1, cur0, cur1, ssum, curA);
    k_scatterA<<<dim3(NBLKA,2), 256, 0, stream>>>(ei0, ei1, curA, tmp0, tmp1);
    k_scatterB<<<dim3(NBUCK,2), 256, 0, stream>>>(tmp0, tmp1, base0, base1,
                                                  cur0, cur1, srt0, srt1);
    k_gather<<<dim3((NN + 3)/4, 2), 256, 0, stream>>>(
        srt0, srt1, base0, base1, a_src0, a_dst0, a_src1, a_dst1, xp, o0, o1);

    k_semantic<<<dim3((NN/16 + 3)/4, 2), 256, 0, stream>>>(
        o0, o1, WkThi, WkTlo, wconv + W_BK, wconv + W_Q, scores);
    k_beta<<<1, 1, 0, stream>>>(scores, beta);
    k_final<<<NN/16, 256, 0, stream>>>(o0, o1, beta, wconv + W_WL, wconv + W_BL,
                                       flag, d_out);
}

// Round 9
// 612.354 us; speedup vs baseline: 1.3867x; 1.1309x over previous
//
#include <hip/hip_runtime.h>
#include <hip/hip_bf16.h>

#define NN 50000
#define EE 1000000
#define FIN 512
#define HIDDEN 128
#define NH 8
#define DH 16
#define NOUT 3
#define NBUCK 196   // ceil(NN/256) coarse dst buckets
#define EPB 8192    // edges per block in scatterA
#define NBLKA ((EE + EPB - 1) / EPB)

typedef unsigned short u16;
typedef unsigned int u32;
typedef __attribute__((ext_vector_type(8))) short short8;
typedef __attribute__((ext_vector_type(4))) float f32x4;

__device__ __forceinline__ float b2f(u16 b) { return __uint_as_float(((u32)b) << 16); }
__device__ __forceinline__ u16 f2b(float f) { return (u16)(__float_as_uint(f) >> 16); }
__device__ __forceinline__ u16 f2b_rne(float f) {
    u32 u = __float_as_uint(f);
    return (u16)((u + 0x7FFFu + ((u >> 16) & 1u)) >> 16);
}

// Converted-weight layout (fp32), offsets within wconv:
#define W_WP   0
#define W_BP   65536
#define W_AS0  65664
#define W_AD0  65792
#define W_AS1  65920
#define W_AD1  66048
#define W_WK   66176
#define W_BK   82560
#define W_Q    82688
#define W_WL   82816
#define W_BL   83200
#define W_TOT  83203

// ---------------- Dtype detection ----------------
__global__ void k_detect(const void* __restrict__ x, int* __restrict__ flag)
{
    const u16* xb = (const u16*)x;
    int t = threadIdx.x;
    int insane = 0;
    #pragma unroll
    for (int i = 0; i < 16; ++i) {
        int idx = ((t * 16 + i) * 131) * 2;
        float v = b2f(xb[idx]);
        float a = fabsf(v);
        bool sane = (a == 0.0f) || (a >= 1e-8f && a <= 1e4f);
        insane += sane ? 0 : 1;
    }
    __shared__ int red[256];
    red[t] = insane;
    __syncthreads();
    for (int s = 128; s > 0; s >>= 1) { if (t < s) red[t] += red[t + s]; __syncthreads(); }
    if (t == 0) flag[0] = (red[0] > 1024) ? 1 : 0;   // 1 = fp32 inputs, 0 = bf16
}

// ---------------- Convert all small weights to canonical fp32 ----------------
__global__ __launch_bounds__(256) void k_convert(
    const void* Wp, const void* bp, const void* as0, const void* ad0,
    const void* as1, const void* ad1, const void* Wk, const void* bk,
    const void* q, const void* Wl, const void* bl,
    const int* __restrict__ flag, float* __restrict__ W)
{
    int i = blockIdx.x * 256 + threadIdx.x;
    if (i >= W_TOT) return;
    const void* src; int off;
    if      (i < W_BP)  { src = Wp;  off = i; }
    else if (i < W_AS0) { src = bp;  off = i - W_BP; }
    else if (i < W_AD0) { src = as0; off = i - W_AS0; }
    else if (i < W_AS1) { src = ad0; off = i - W_AD0; }
    else if (i < W_AD1) { src = as1; off = i - W_AS1; }
    else if (i < W_WK)  { src = ad1; off = i - W_AD1; }
    else if (i < W_BK)  { src = Wk;  off = i - W_WK; }
    else if (i < W_Q)   { src = bk;  off = i - W_BK; }
    else if (i < W_WL)  { src = q;   off = i - W_Q; }
    else if (i < W_BL)  { src = Wl;  off = i - W_WL; }
    else                { src = bl;  off = i - W_BL; }
    float v = flag[0] ? ((const float*)src)[off] : b2f(((const u16*)src)[off]);
    W[i] = v;
}

// ---------------- Prep: W_proj^T (hi/lo) and Wk^T (hi only) as bf16 ----------------
#define PREPN (FIN*HIDDEN + HIDDEN*HIDDEN)   // 65536 + 16384
__global__ __launch_bounds__(256) void k_prepw(
    const float* __restrict__ Wpf, const float* __restrict__ Wkf,
    u16* __restrict__ WhiT, u16* __restrict__ WloT, u16* __restrict__ WkThi)
{
    int idx = blockIdx.x*256 + threadIdx.x;
    if (idx >= PREPN) return;
    if (idx < FIN*HIDDEN) {
        int k = idx >> 7, n = idx & 127;
        float w = Wpf[idx];
        u32 hb = __float_as_uint(w) & 0xFFFF0000u;
        WhiT[(size_t)n*FIN + k] = (u16)(hb >> 16);
        WloT[(size_t)n*FIN + k] = f2b(w - __uint_as_float(hb));
    } else {
        int i = idx - FIN*HIDDEN;
        int k = i >> 7, h = i & 127;
        WkThi[(size_t)h*HIDDEN + k] = f2b_rne(Wkf[i]);
    }
}

// ---------------- Projection via MFMA, split-bf16; output packed bf16 xpb ----------------
__global__ __launch_bounds__(256) void k_projm(
    const void* __restrict__ x, const u16* __restrict__ WhiT,
    const u16* __restrict__ WloT, const float* __restrict__ bpf,
    const int* __restrict__ flag, u16* __restrict__ xpb)
{
    const int t = threadIdx.x;
    const int lane = t & 63;
    const int w = t >> 6;
    const int m16 = lane & 15;
    const int quad = lane >> 4;
    const int f = flag[0];
    int row = blockIdx.x*64 + w*16 + m16;
    int rowc = row < NN ? row : NN-1;

    f32x4 acc[8];
    #pragma unroll
    for (int i=0;i<8;++i) acc[i] = (f32x4)(0.f);

    for (int kt = 0; kt < FIN; kt += 32) {
        int kbase = kt + quad*8;
        short8 ahi, alo;
        if (f) {
            const float* px = (const float*)x + (size_t)rowc*FIN + kbase;
            float4 v0 = *(const float4*)px;
            float4 v1 = *(const float4*)(px+4);
            float xv[8] = {v0.x,v0.y,v0.z,v0.w,v1.x,v1.y,v1.z,v1.w};
            #pragma unroll
            for (int j=0;j<8;++j) {
                u32 hb = __float_as_uint(xv[j]) & 0xFFFF0000u;
                ahi[j] = (short)(hb >> 16);
                alo[j] = (short)f2b(xv[j] - __uint_as_float(hb));
            }
        } else {
            const u16* px = (const u16*)x + (size_t)rowc*FIN + kbase;
            ushort4 v0 = *(const ushort4*)px;
            ushort4 v1 = *(const ushort4*)(px+4);
            ahi[0]=v0.x; ahi[1]=v0.y; ahi[2]=v0.z; ahi[3]=v0.w;
            ahi[4]=v1.x; ahi[5]=v1.y; ahi[6]=v1.z; ahi[7]=v1.w;
            alo = (short8)(short)0;
        }
        #pragma unroll
        for (int nt = 0; nt < 8; ++nt) {
            int n = nt*16 + m16;
            short8 bhi = *(const short8*)(WhiT + (size_t)n*FIN + kbase);
            short8 blo = *(const short8*)(WloT + (size_t)n*FIN + kbase);
            acc[nt] = __builtin_amdgcn_mfma_f32_16x16x32_bf16(ahi, bhi, acc[nt], 0,0,0);
            acc[nt] = __builtin_amdgcn_mfma_f32_16x16x32_bf16(ahi, blo, acc[nt], 0,0,0);
            acc[nt] = __builtin_amdgcn_mfma_f32_16x16x32_bf16(alo, bhi, acc[nt], 0,0,0);
        }
    }
    int orow0 = blockIdx.x*64 + w*16 + quad*4;
    #pragma unroll
    for (int nt=0; nt<8; ++nt) {
        int col = nt*16 + m16;
        float bias = bpf[col];
        #pragma unroll
        for (int r=0;r<4;++r) {
            int orow = orow0 + r;
            if (orow < NN) xpb[(size_t)orow*HIDDEN + col] = f2b_rne(acc[nt][r] + bias);
        }
    }
}

// ---------------- Attention coefficients (bf16 xpb input) ----------------
__global__ __launch_bounds__(256) void k_attcoef(
    const u16* __restrict__ xpb, const float* __restrict__ watt,
    float* __restrict__ o_as0, float* __restrict__ o_ad0,
    float* __restrict__ o_as1, float* __restrict__ o_ad1)
{
    __shared__ float s0[128], d0[128], s1[128], d1[128];
    const int t = threadIdx.x;
    if (t < 128) { s0[t]=watt[t]; d0[t]=watt[128+t]; s1[t]=watt[256+t]; d1[t]=watt[384+t]; }
    __syncthreads();
    int tid = blockIdx.x*256 + t;               // n*8 + h
    if (tid >= NN*NH) return;
    int h = tid & 7;
    const u32* px = (const u32*)(xpb + (size_t)tid * DH);
    float xv[16];
    #pragma unroll
    for (int i=0;i<8;++i){ u32 v=px[i]; xv[i*2]=b2f((u16)(v&0xFFFF)); xv[i*2+1]=b2f((u16)(v>>16)); }
    float r0=0.f,r1=0.f,r2=0.f,r3=0.f;
    #pragma unroll
    for (int d=0; d<16; ++d) {
        float xvd = xv[d];
        r0 += xvd*s0[h*16+d]; r1 += xvd*d0[h*16+d];
        r2 += xvd*s1[h*16+d]; r3 += xvd*d1[h*16+d];
    }
    o_as0[tid]=r0; o_ad0[tid]=r1; o_as1[tid]=r2; o_ad1[tid]=r3;
}

// ---------------- CSR phase 1: histogram of dst ----------------
__global__ __launch_bounds__(256) void k_hist(
    const int* __restrict__ ei0, const int* __restrict__ ei1,
    int* __restrict__ cnt0, int* __restrict__ cnt1)
{
    int gid = blockIdx.x*256 + threadIdx.x;
    if (gid < EE)           atomicAdd(&cnt0[ei0[EE + gid]], 1);
    else if (gid < 2*EE)    atomicAdd(&cnt1[ei1[gid]], 1);
}

// ---------------- CSR phase 2: three-step parallel exclusive scan ----------------
#define NCH 49   // ceil(50001/1024)
__global__ __launch_bounds__(1024) void k_scan1(
    int* __restrict__ base0, int* __restrict__ base1, int* __restrict__ ssum)
{
    int mp = blockIdx.y;
    int* base = mp ? base1 : base0;
    __shared__ int s[1024];
    const int t = threadIdx.x;
    int i = blockIdx.x*1024 + t;
    int v = (i <= NN) ? base[i] : 0;
    s[t] = v;
    __syncthreads();
    for (int off = 1; off < 1024; off <<= 1) {
        int u = (t >= off) ? s[t - off] : 0;
        __syncthreads();
        s[t] += u;
        __syncthreads();
    }
    if (i <= NN) base[i] = s[t] - v;
    if (t == 1023) ssum[mp*64 + blockIdx.x] = s[1023];
}
__global__ void k_scan2(int* __restrict__ ssum)
{
    int t = threadIdx.x;
    if (t < 2) {
        int c = 0;
        for (int j = 0; j < NCH; ++j) { int v = ssum[t*64+j]; ssum[t*64+j] = c; c += v; }
    }
}
__global__ __launch_bounds__(1024) void k_scan3(
    int* __restrict__ base0, int* __restrict__ base1,
    int* __restrict__ cur0, int* __restrict__ cur1,
    const int* __restrict__ ssum, int* __restrict__ curA)
{
    int mp = blockIdx.y;
    int* base = mp ? base1 : base0;
    int* cur  = mp ? cur1  : cur0;
    int off = ssum[mp*64 + blockIdx.x];
    int i = blockIdx.x*1024 + threadIdx.x;
    if (i <= NN) {
        int b = base[i] + off;
        base[i] = b;
        if (i < NN) {
            cur[i] = b;
            if ((i & 255) == 0) curA[(mp*256 + (i >> 8)) * 16] = b;
        }
    }
}

// ---------------- Scatter pass A: reserve-segment coarse binning ----------------
__global__ __launch_bounds__(256) void k_scatterA(
    const int* __restrict__ ei0, const int* __restrict__ ei1,
    int* __restrict__ curA, int2* __restrict__ tmp0, int2* __restrict__ tmp1)
{
    const int mp = blockIdx.y;
    const int* ei = mp ? ei1 : ei0;
    int2* tmp = mp ? tmp1 : tmp0;
    __shared__ int hist[NBUCK];
    __shared__ int seg[NBUCK];
    __shared__ int cnt[NBUCK];
    const int t = threadIdx.x;
    for (int b = t; b < NBUCK; b += 256) hist[b] = 0;
    __syncthreads();
    const int e0 = blockIdx.x * EPB;
    #pragma unroll
    for (int i = 0; i < EPB/256; ++i) {
        int idx = e0 + i*256 + t;
        if (idx < EE) atomicAdd(&hist[ei[EE + idx] >> 8], 1);
    }
    __syncthreads();
    for (int b = t; b < NBUCK; b += 256) {
        int h = hist[b];
        seg[b] = h ? atomicAdd(&curA[(mp*256 + b)*16], h) : 0;
        cnt[b] = 0;
    }
    __syncthreads();
    #pragma unroll
    for (int i = 0; i < EPB/256; ++i) {
        int idx = e0 + i*256 + t;
        if (idx < EE) {
            int s = ei[idx], d = ei[EE + idx];
            int b = d >> 8;
            int pos = seg[b] + atomicAdd(&cnt[b], 1);
            tmp[pos] = make_int2(s, d);
        }
    }
}

// ---------------- Scatter pass B: exact CSR position, one block per bucket ----------------
__global__ __launch_bounds__(256) void k_scatterB(
    const int2* __restrict__ tmp0, const int2* __restrict__ tmp1,
    const int* __restrict__ base0, const int* __restrict__ base1,
    int* __restrict__ cur0, int* __restrict__ cur1,
    int* __restrict__ srt0, int* __restrict__ srt1)
{
    const int b = blockIdx.x;
    const int mp = blockIdx.y;
    const int2* tmp = mp ? tmp1 : tmp0;
    const int* base = mp ? base1 : base0;
    int* cur = mp ? cur1 : cur0;
    int* srt = mp ? srt1 : srt0;
    int lo = base[b << 8];
    int hiIdx = (b + 1) << 8; if (hiIdx > NN) hiIdx = NN;
    int hi = base[hiIdx];
    for (int i = lo + threadIdx.x; i < hi; i += 256) {
        int2 sd = tmp[i];
        int pos = atomicAdd(&cur[sd.y], 1);
        srt[pos] = sd.x;
    }
}

// ---------------- Gather: bf16 xpb in, bf16 obf out; fused softmax; 4x unroll ----------------
__global__ __launch_bounds__(256) void k_gather(
    const int* __restrict__ srt0, const int* __restrict__ srt1,
    const int* __restrict__ base0, const int* __restrict__ base1,
    const float* __restrict__ as0, const float* __restrict__ ad0,
    const float* __restrict__ as1, const float* __restrict__ ad1,
    const u16* __restrict__ xpb, u16* __restrict__ obf0, u16* __restrict__ obf1)
{
    const int t = threadIdx.x;
    const int wid = blockIdx.x*4 + (t >> 6);
    if (wid >= NN) return;
    const int lane = t & 63;
    const int h = lane >> 3;
    const int mp = blockIdx.y;
    const int*  srt  = mp ? srt1  : srt0;
    const int*  base = mp ? base1 : base0;
    const float* asr = mp ? as1 : as0;
    const float* ads = mp ? ad1 : ad0;
    u16* obf = mp ? obf1 : obf0;
    const u32* xw = (const u32*)xpb;     // 64 u32 per row

    const int b = base[wid], e = base[wid + 1];
    const float advl = ads[wid*NH + h];
    float accx = 0.f, accy = 0.f, den = 0.f;
    int i = b;
    for (; i + 4 <= e; i += 4) {
        int s0 = srt[i], s1 = srt[i+1], s2 = srt[i+2], s3 = srt[i+3];
        float r0 = asr[s0*NH + h], r1 = asr[s1*NH + h];
        float r2 = asr[s2*NH + h], r3 = asr[s3*NH + h];
        u32 v0 = xw[(size_t)s0*64 + lane];
        u32 v1 = xw[(size_t)s1*64 + lane];
        u32 v2 = xw[(size_t)s2*64 + lane];
        u32 v3 = xw[(size_t)s3*64 + lane];
        float a0 = r0+advl; a0 = a0>0.f ? a0 : 0.2f*a0; float e0 = __expf(a0);
        float a1 = r1+advl; a1 = a1>0.f ? a1 : 0.2f*a1; float e1 = __expf(a1);
        float a2 = r2+advl; a2 = a2>0.f ? a2 : 0.2f*a2; float e2 = __expf(a2);
        float a3 = r3+advl; a3 = a3>0.f ? a3 : 0.2f*a3; float e3 = __expf(a3);
        accx += e0*b2f((u16)(v0&0xFFFF)) + e1*b2f((u16)(v1&0xFFFF))
              + e2*b2f((u16)(v2&0xFFFF)) + e3*b2f((u16)(v3&0xFFFF));
        accy += e0*b2f((u16)(v0>>16)) + e1*b2f((u16)(v1>>16))
              + e2*b2f((u16)(v2>>16)) + e3*b2f((u16)(v3>>16));
        den  += e0 + e1 + e2 + e3;
    }
    for (; i < e; ++i) {
        int s = srt[i];
        float a = asr[s*NH + h] + advl;
        a = a > 0.f ? a : 0.2f*a;
        float ex = __expf(a);
        u32 v = xw[(size_t)s*64 + lane];
        accx += ex*b2f((u16)(v&0xFFFF)); accy += ex*b2f((u16)(v>>16)); den += ex;
    }
    float inv = 1.f / (den + 1e-16f);
    u32 lo = f2b_rne(accx*inv), hi = f2b_rne(accy*inv);
    ((u32*)obf)[(size_t)wid*64 + lane] = (hi << 16) | lo;
}

// ---------------- Semantic scores via MFMA (bf16 obf direct A-operand) ----------------
__global__ __launch_bounds__(256) void k_semantic(
    const u16* __restrict__ obf0, const u16* __restrict__ obf1,
    const u16* __restrict__ WkThi, const float* __restrict__ bkf,
    const float* __restrict__ qf, float* __restrict__ scores)
{
    const int t = threadIdx.x;
    const int lane = t & 63;
    const int w = t >> 6;
    const int m16 = lane & 15;
    const int quad = lane >> 4;
    const int mp = blockIdx.y;
    const u16* om = mp ? obf1 : obf0;
    const int tile = blockIdx.x*4 + w;

    float partial = 0.f;
    if (tile < NN/16) {
        int row = tile*16 + m16;
        f32x4 acc[8];
        #pragma unroll
        for (int i=0;i<8;++i) acc[i] = (f32x4)(0.f);

        for (int kt = 0; kt < HIDDEN; kt += 32) {
            int kbase = kt + quad*8;
            short8 a = *(const short8*)(om + (size_t)row*HIDDEN + kbase);
            #pragma unroll
            for (int j=0;j<8;++j) a[j] = ((u16)a[j] & 0x8000u) ? (short)0 : a[j];  // relu in bf16
            #pragma unroll
            for (int nt = 0; nt < 8; ++nt) {
                int n = nt*16 + m16;
                short8 bhi = *(const short8*)(WkThi + (size_t)n*HIDDEN + kbase);
                acc[nt] = __builtin_amdgcn_mfma_f32_16x16x32_bf16(a, bhi, acc[nt], 0,0,0);
            }
        }
        #pragma unroll
        for (int nt=0; nt<8; ++nt) {
            int col = nt*16 + m16;
            float bkv = bkf[col], qv = qf[col];
            #pragma unroll
            for (int r=0;r<4;++r)
                partial += qv * tanhf(acc[nt][r] + bkv);
        }
    }
    __shared__ float red[256];
    red[t] = partial;
    __syncthreads();
    for (int s2 = 128; s2 > 0; s2 >>= 1) {
        if (t < s2) red[t] += red[t + s2];
        __syncthreads();
    }
    if (t == 0) unsafeAtomicAdd(&scores[mp], red[0]);
}

// ---------------- Beta ----------------
__global__ void k_beta(const float* __restrict__ scores, float* __restrict__ beta)
{
    float s0 = scores[0] / (float)NN;
    float s1 = scores[1] / (float)NN;
    float m = fmaxf(s0, s1);
    float e0 = __expf(s0-m), e1 = __expf(s1-m);
    float inv = 1.f/(e0+e1);
    beta[0] = e0*inv; beta[1] = e1*inv;
}

// ---------------- Final head (bf16 obf inputs) ----------------
__global__ __launch_bounds__(256) void k_final(
    const u16* __restrict__ obf0, const u16* __restrict__ obf1,
    const float* __restrict__ beta, const float* __restrict__ Wlf,
    const float* __restrict__ blf, const int* __restrict__ flag,
    void* __restrict__ outv)
{
    __shared__ float fus[16*128];
    __shared__ float WlL[384];
    __shared__ float blL[3];
    const int t = threadIdx.x;
    for (int i = t; i < 384; i += 256) WlL[i] = Wlf[i];
    if (t < 3) blL[t] = blf[t];
    float b0 = beta[0], b1 = beta[1];
    const u32* o0w = (const u32*)obf0;
    const u32* o1w = (const u32*)obf1;
    size_t base = (size_t)blockIdx.x * 16 * 64;   // u32 units
    #pragma unroll
    for (int i=0;i<4;++i) {
        int j = t + i*256;                         // 0..1023
        u32 v0 = o0w[base + j];
        u32 v1 = o1w[base + j];
        float l0 = fmaxf(b2f((u16)(v0&0xFFFF)),0.f), h0 = fmaxf(b2f((u16)(v0>>16)),0.f);
        float l1 = fmaxf(b2f((u16)(v1&0xFFFF)),0.f), h1 = fmaxf(b2f((u16)(v1>>16)),0.f);
        int row = j >> 6, cp = j & 63;
        fus[row*128 + cp*2]     = b0*l0 + b1*l1;
        fus[row*128 + cp*2 + 1] = b0*h0 + b1*h1;
    }
    __syncthreads();
    if (t < 48) {
        int node = t / 3, c = t % 3;
        float acc = blL[c];
        const float* fr = &fus[node*128];
        #pragma unroll 16
        for (int k=0;k<128;++k) acc += fr[k]*WlL[k*3+c];
        size_t oi = (size_t)(blockIdx.x*16 + node)*NOUT + c;
        if (flag[0]) ((float*)outv)[oi] = acc;
        else         ((__hip_bfloat16*)outv)[oi] = __float2bfloat16(acc);
    }
}

extern "C" void kernel_launch(void* const* d_in, const int* in_sizes, int n_in,
                              void* d_out, int out_size, void* d_ws, size_t ws_size,
                              hipStream_t stream)
{
    const void* x   = d_in[0];
    const int* ei0  = (const int*)d_in[1];
    const int* ei1  = (const int*)d_in[2];

    float* ws = (float*)d_ws;
    u16*   xpb     = (u16*)ws;                  // 6.4M u16 = 3,200,000 f
    float* a_src0  = ws +  3200000;
    float* a_dst0  = ws +  3600000;
    float* a_src1  = ws +  4000000;
    float* a_dst1  = ws +  4400000;
    u16*   obf0    = (u16*)(ws + 4800000);      // 3,200,000 f
    u16*   obf1    = (u16*)(ws + 8000000);      // 3,200,000 f
    int*   srt0    = (int*)(ws + 11200000);     // 1,000,000
    int*   srt1    = (int*)(ws + 12200000);     // 1,000,000
    int2*  tmp0    = (int2*)(ws + 13200000);    // 4,000,000 f
    int2*  tmp1    = (int2*)(ws + 17200000);    // 4,000,000 f
    int*   base0   = (int*)(ws + 21200000);     // 50,004
    int*   base1   = (int*)(ws + 21250004);     // 50,004
    float* scores  = ws + 21300008;             // 2
    int*   cur0    = (int*)(ws + 21300010);     // 50,000
    int*   cur1    = (int*)(ws + 21350010);     // 50,000
    float* beta    = ws + 21400010;             // 2
    int*   flag    = (int*)(ws + 21400012);     // 4 pad
    float* wconv   = ws + 21400016;             // 83,203
    int*   ssum    = (int*)(ws + 21483220);     // 128
    int*   curA    = (int*)(ws + 21483348);     // 8,192 ints (64B-padded)
    u16*   WhiT    = (u16*)(ws + 21491540);     // 65,536 u16
    u16*   WloT    = (u16*)(ws + 21524308);     // 65,536 u16
    u16*   WkThi   = (u16*)(ws + 21557076);     // 16,384 u16
    // end ≈ 21,565,268 floats ≈ 86.3 MB

    hipMemsetAsync(base0, 0, (size_t)100010 * sizeof(int), stream);

    k_detect<<<1, 256, 0, stream>>>(x, flag);
    k_convert<<<(W_TOT+255)/256, 256, 0, stream>>>(
        d_in[3], d_in[4], d_in[5], d_in[6], d_in[7], d_in[8],
        d_in[9], d_in[10], d_in[11], d_in[12], d_in[13], flag, wconv);
    k_prepw<<<(PREPN+255)/256, 256, 0, stream>>>(wconv + W_WP, wconv + W_WK,
                                                 WhiT, WloT, WkThi);

    k_projm<<<(NN+63)/64, 256, 0, stream>>>(x, WhiT, WloT, wconv + W_BP, flag, xpb);
    k_attcoef<<<(NN*NH + 255)/256, 256, 0, stream>>>(xpb, wconv + W_AS0,
                                                     a_src0, a_dst0, a_src1, a_dst1);
    k_hist<<<(2*EE + 255)/256, 256, 0, stream>>>(ei0, ei1, base0, base1);
    k_scan1<<<dim3(NCH,2), 1024, 0, stream>>>(base0, base1, ssum);
    k_scan2<<<1, 64, 0, stream>>>(ssum);
    k_scan3<<<dim3(NCH,2), 1024, 0, stream>>>(base0, base1, cur0, cur1, ssum, curA);
    k_scatterA<<<dim3(NBLKA,2), 256, 0, stream>>>(ei0, ei1, curA, tmp0, tmp1);
    k_scatterB<<<dim3(NBUCK,2), 256, 0, stream>>>(tmp0, tmp1, base0, base1,
                                                  cur0, cur1, srt0, srt1);
    k_gather<<<dim3((NN + 3)/4, 2), 256, 0, stream>>>(
        srt0, srt1, base0, base1, a_src0, a_dst0, a_src1, a_dst1, xpb, obf0, obf1);

    k_semantic<<<dim3((NN/16 + 3)/4, 2), 256, 0, stream>>>(
        obf0, obf1, WkThi, wconv + W_BK, wconv + W_Q, scores);
    k_beta<<<1, 1, 0, stream>>>(scores, beta);
    k_final<<<NN/16, 256, 0, stream>>>(obf0, obf1, beta, wconv + W_WL, wconv + W_BL,
                                       flag, d_out);
}